// Round 5
// baseline (980.409 us; speedup 1.0000x reference)
//
#include <hip/hip_runtime.h>
#include <math.h>

#define NPROP 1000
#define CCH 256
#define FH 100
#define FW 100
#define POOLSZ 7
#define FEAT 12544   // 256*49
#define HID 1024
#define NCLS 21
#define NHEAD 105    // 21 + 84
#define NCAND 20000  // 1000 * 20
#define SCORE_T 0.05f
#define NMS_T 0.5f
#define MAXDET 100

typedef _Float16 f16;
typedef __attribute__((ext_vector_type(8))) _Float16 f16x8;
typedef __attribute__((ext_vector_type(4))) float f32x4;

// ---------------- transpose fm [256,100,100] -> fmT [100*100, 256] ----------------
__global__ __launch_bounds__(256) void k_transpose(const float* __restrict__ fm,
                                                   float* __restrict__ fmT) {
    __shared__ float lds[64 * 257];
    int posbase = blockIdx.x * 64;
    int tid = threadIdx.x;
    int cq = tid >> 6;   // 0..3
    int pl = tid & 63;   // 0..63
    int pos = posbase + pl;
    bool pok = pos < FH * FW;
    for (int c0 = 0; c0 < CCH; c0 += 4) {
        int c = c0 + cq;
        float v = pok ? fm[c * (FH * FW) + pos] : 0.f;
        lds[pl * 257 + c] = v;
    }
    __syncthreads();
    for (int p = 0; p < 64; ++p) {
        int pos2 = posbase + p;
        if (pos2 < FH * FW) fmT[(size_t)pos2 * CCH + tid] = lds[p * 257 + tid];
    }
}

// ---------------- ROI align: pooled [1000][12544], k = c*49 + py*7 + px ----------------
__global__ __launch_bounds__(256) void k_roi(const float* __restrict__ fmT,
                                             const float* __restrict__ rois,
                                             float* __restrict__ pooled) {
    int n = blockIdx.x;
    int tid = threadIdx.x;
    __shared__ float wx0[14], wx1[14], wy0[14], wy1[14];
    __shared__ int ix0[14], ix1[14], iy0[14], iy1[14], vx[14], vy[14];
    __shared__ float outb[FEAT];

    if (tid < 28) {
        int axis = tid / 14;  // 0=x, 1=y
        int j = tid % 14;
        float p0 = rois[n * 4 + axis];
        float p1 = rois[n * 4 + 2 + axis];
        float b0 = p0 * 0.125f - 0.5f;
        float b1 = p1 * 0.125f - 0.5f;
        float bsz = (b1 - b0) / 7.0f;
        int p = j >> 1, s = j & 1;
        float off = (float)p + ((float)s + 0.5f) / 2.0f;
        float v = b0 + off * bsz;
        float size = 100.0f;
        int valid = (v >= -1.0f && v <= size) ? 1 : 0;
        v = fminf(fmaxf(v, 0.0f), size - 1.0f);
        float v0 = floorf(v);
        int i0 = (int)v0;
        int i1 = min(i0 + 1, 99);
        float w1v = v - v0;
        float w0v = 1.0f - w1v;
        if (axis == 0) { ix0[j] = i0 * CCH; ix1[j] = i1 * CCH; wx0[j] = w0v; wx1[j] = w1v; vx[j] = valid; }
        else           { iy0[j] = i0 * (FW * CCH); iy1[j] = i1 * (FW * CCH); wy0[j] = w0v; wy1[j] = w1v; vy[j] = valid; }
    }
    __syncthreads();

    int c = tid;
    for (int py = 0; py < POOLSZ; ++py) {
        for (int px = 0; px < POOLSZ; ++px) {
            float acc = 0.f;
            #pragma unroll
            for (int sy = 0; sy < 2; ++sy) {
                int jy = py * 2 + sy;
                if (!vy[jy]) continue;
                float fy0 = wy0[jy], fy1 = wy1[jy];
                int y0 = iy0[jy], y1 = iy1[jy];
                #pragma unroll
                for (int sx = 0; sx < 2; ++sx) {
                    int jx = px * 2 + sx;
                    if (!vx[jx]) continue;
                    float fx0 = wx0[jx], fx1 = wx1[jx];
                    int x0 = ix0[jx], x1 = ix1[jx];
                    float a00 = fmT[y0 + x0 + c];
                    float a01 = fmT[y0 + x1 + c];
                    float a10 = fmT[y1 + x0 + c];
                    float a11 = fmT[y1 + x1 + c];
                    acc += fy0 * (fx0 * a00 + fx1 * a01) + fy1 * (fx0 * a10 + fx1 * a11);
                }
            }
            outb[c * 49 + py * 7 + px] = acc * 0.25f;
        }
    }
    __syncthreads();
    size_t base = (size_t)n * FEAT;
    for (int o = tid; o < FEAT; o += 256)
        pooled[base + o] = outb[o];
}

// ---------------- MFMA GEMM, f16 3-pass split (fp32-class accuracy) ----------------
__global__ __launch_bounds__(256) void k_gemm_mfma(const float* __restrict__ A,
                                                   const float* __restrict__ B,
                                                   float* __restrict__ P,
                                                   int M, int K, int nt) {
    __shared__ f16 Ah[2][2048], Al[2][2048], Bh[2][2048], Bl[2][2048];
    int tid = threadIdx.x;
    int n0 = blockIdx.x * 64;
    int m0 = blockIdx.y * 64;
    int kz = blockIdx.z;
    int kbase0 = kz * nt * 32;

    int a_row = tid >> 2;   // 0..63
    int a_kq  = tid & 3;    // 0..3 (8 k's each)
    int b_n   = tid & 63;
    int b_kg  = tid >> 6;   // == wave id

    int wave = tid >> 6, lane = tid & 63;
    int wr = (wave >> 1) * 32, wc = (wave & 1) * 32;
    int lhi = lane >> 4, llo = lane & 15;

    f32x4 accm[2][2] = {};
    f32x4 accc[2][2] = {};

    float aS[8], bS[8];
    const float* Arow = A + (size_t)(m0 + a_row) * K;
    bool arow_ok = (m0 + a_row) < M;

    int a_st = a_kq * 512 + ((a_row ^ a_kq) << 3);
    int b_st = b_kg * 512 + (b_n << 3);
    int a_rd0 = lhi * 512 + (((wr + 0  + llo) ^ lhi) << 3);
    int a_rd1 = lhi * 512 + (((wr + 16 + llo) ^ lhi) << 3);
    int b_rd0 = lhi * 512 + ((wc + 0  + llo) << 3);
    int b_rd1 = lhi * 512 + ((wc + 16 + llo) << 3);

    auto LOAD = [&](int t) {
        int kb = kbase0 + t * 32;
        if (arow_ok) {
            const float* ap = Arow + kb + a_kq * 8;
            float4 v0 = *(const float4*)(ap);
            float4 v1 = *(const float4*)(ap + 4);
            aS[0] = v0.x; aS[1] = v0.y; aS[2] = v0.z; aS[3] = v0.w;
            aS[4] = v1.x; aS[5] = v1.y; aS[6] = v1.z; aS[7] = v1.w;
        } else {
            #pragma unroll
            for (int j = 0; j < 8; ++j) aS[j] = 0.f;
        }
        const float* bp = B + (size_t)(kb + b_kg * 8) * 1024 + n0 + b_n;
        #pragma unroll
        for (int j = 0; j < 8; ++j) bS[j] = bp[(size_t)j * 1024];
    };
    auto STORE = [&](int buf) {
        f16x8 vh, vl;
        #pragma unroll
        for (int j = 0; j < 8; ++j) {
            f16 h = (f16)aS[j];
            vh[j] = h;
            vl[j] = (f16)((aS[j] - (float)h) * 4096.0f);
        }
        *(f16x8*)&Ah[buf][a_st] = vh;
        *(f16x8*)&Al[buf][a_st] = vl;
        #pragma unroll
        for (int j = 0; j < 8; ++j) {
            f16 h = (f16)bS[j];
            vh[j] = h;
            vl[j] = (f16)((bS[j] - (float)h) * 4096.0f);
        }
        *(f16x8*)&Bh[buf][b_st] = vh;
        *(f16x8*)&Bl[buf][b_st] = vl;
    };

    LOAD(0);
    STORE(0);
    __syncthreads();

    for (int t = 0; t < nt; ++t) {
        int cur = t & 1;
        if (t + 1 < nt) LOAD(t + 1);
        {
            f16x8 ah0 = *(f16x8*)&Ah[cur][a_rd0];
            f16x8 ah1 = *(f16x8*)&Ah[cur][a_rd1];
            f16x8 bh0 = *(f16x8*)&Bh[cur][b_rd0];
            f16x8 bh1 = *(f16x8*)&Bh[cur][b_rd1];
            f16x8 al0 = *(f16x8*)&Al[cur][a_rd0];
            f16x8 al1 = *(f16x8*)&Al[cur][a_rd1];
            f16x8 bl0 = *(f16x8*)&Bl[cur][b_rd0];
            f16x8 bl1 = *(f16x8*)&Bl[cur][b_rd1];
            accm[0][0] = __builtin_amdgcn_mfma_f32_16x16x32_f16(ah0, bh0, accm[0][0], 0, 0, 0);
            accm[0][1] = __builtin_amdgcn_mfma_f32_16x16x32_f16(ah0, bh1, accm[0][1], 0, 0, 0);
            accm[1][0] = __builtin_amdgcn_mfma_f32_16x16x32_f16(ah1, bh0, accm[1][0], 0, 0, 0);
            accm[1][1] = __builtin_amdgcn_mfma_f32_16x16x32_f16(ah1, bh1, accm[1][1], 0, 0, 0);
            accc[0][0] = __builtin_amdgcn_mfma_f32_16x16x32_f16(ah0, bl0, accc[0][0], 0, 0, 0);
            accc[0][1] = __builtin_amdgcn_mfma_f32_16x16x32_f16(ah0, bl1, accc[0][1], 0, 0, 0);
            accc[1][0] = __builtin_amdgcn_mfma_f32_16x16x32_f16(ah1, bl0, accc[1][0], 0, 0, 0);
            accc[1][1] = __builtin_amdgcn_mfma_f32_16x16x32_f16(ah1, bl1, accc[1][1], 0, 0, 0);
            accc[0][0] = __builtin_amdgcn_mfma_f32_16x16x32_f16(al0, bh0, accc[0][0], 0, 0, 0);
            accc[0][1] = __builtin_amdgcn_mfma_f32_16x16x32_f16(al0, bh1, accc[0][1], 0, 0, 0);
            accc[1][0] = __builtin_amdgcn_mfma_f32_16x16x32_f16(al1, bh0, accc[1][0], 0, 0, 0);
            accc[1][1] = __builtin_amdgcn_mfma_f32_16x16x32_f16(al1, bh1, accc[1][1], 0, 0, 0);
        }
        if (t + 1 < nt) {
            STORE(cur ^ 1);
            __syncthreads();
        }
    }

    const float inv = 1.0f / 4096.0f;
    #pragma unroll
    for (int mi = 0; mi < 2; ++mi) {
        #pragma unroll
        for (int r = 0; r < 4; ++r) {
            int row = m0 + wr + mi * 16 + lhi * 4 + r;
            if (row < M) {
                #pragma unroll
                for (int ni = 0; ni < 2; ++ni) {
                    int col = n0 + wc + ni * 16 + llo;
                    float v = accm[mi][ni][r] + accc[mi][ni][r] * inv;
                    P[(size_t)kz * 1048576 + (size_t)row * 1024 + col] = v;
                }
            }
        }
    }
}

// ---------------- fuse: out = relu(P0 + P1 + bias), 1000x1024 ----------------
__global__ __launch_bounds__(256) void k_fuse(const float* __restrict__ P,
                                              const float* __restrict__ bias,
                                              float* __restrict__ out) {
    int t = blockIdx.x * 256 + threadIdx.x;   // float4 index, 0..255999
    float4 p0 = ((const float4*)P)[t];
    float4 p1 = ((const float4*)(P + 1048576))[t];
    float4 b  = ((const float4*)bias)[t & 255];
    float4 v;
    v.x = fmaxf(p0.x + p1.x + b.x, 0.f);
    v.y = fmaxf(p0.y + p1.y + b.y, 0.f);
    v.z = fmaxf(p0.z + p1.z + b.z, 0.f);
    v.w = fmaxf(p0.w + p1.w + b.w, 0.f);
    ((float4*)out)[t] = v;
}

// ---------------- heads: logits[1000][105] = x2 @ [wc|wb] + [bc|bb] ----------------
__global__ __launch_bounds__(128) void k_heads(const float* __restrict__ x2,
                                               const float* __restrict__ wc,
                                               const float* __restrict__ bc,
                                               const float* __restrict__ wb,
                                               const float* __restrict__ bb,
                                               float* __restrict__ logits) {
    int r0 = blockIdx.x * 4;
    __shared__ float xs[4][HID];
    for (int i = threadIdx.x; i < 4 * HID; i += 128) {
        int rr = i >> 10, kk = i & 1023;
        xs[rr][kk] = x2[(size_t)(r0 + rr) * HID + kk];
    }
    __syncthreads();
    int j = threadIdx.x;
    if (j < NHEAD) {
        float a0 = 0.f, a1 = 0.f, a2 = 0.f, a3 = 0.f;
        if (j < NCLS) {
            for (int k = 0; k < HID; ++k) {
                float w = wc[k * NCLS + j];
                a0 = fmaf(xs[0][k], w, a0);
                a1 = fmaf(xs[1][k], w, a1);
                a2 = fmaf(xs[2][k], w, a2);
                a3 = fmaf(xs[3][k], w, a3);
            }
            float b = bc[j];
            a0 += b; a1 += b; a2 += b; a3 += b;
        } else {
            int jb = j - NCLS;
            for (int k = 0; k < HID; ++k) {
                float w = wb[k * 84 + jb];
                a0 = fmaf(xs[0][k], w, a0);
                a1 = fmaf(xs[1][k], w, a1);
                a2 = fmaf(xs[2][k], w, a2);
                a3 = fmaf(xs[3][k], w, a3);
            }
            float b = bb[jb];
            a0 += b; a1 += b; a2 += b; a3 += b;
        }
        logits[(size_t)(r0 + 0) * NHEAD + j] = a0;
        logits[(size_t)(r0 + 1) * NHEAD + j] = a1;
        logits[(size_t)(r0 + 2) * NHEAD + j] = a2;
        logits[(size_t)(r0 + 3) * NHEAD + j] = a3;
    }
}

// ---------------- softmax + decode + candidates + class-major offset boxes ----------------
__global__ __launch_bounds__(256) void k_prep(const float* __restrict__ logits,
                                              const float* __restrict__ rois,
                                              float* __restrict__ boxes,
                                              float* __restrict__ cand,
                                              float* __restrict__ boxesT) {
    int n = blockIdx.x * 256 + threadIdx.x;
    if (n >= NPROP) return;
    const float* L = logits + (size_t)n * NHEAD;
    float m = L[0];
    #pragma unroll
    for (int k = 1; k < NCLS; ++k) m = fmaxf(m, L[k]);
    float sum = 0.f;
    #pragma unroll
    for (int k = 0; k < NCLS; ++k) sum += expf(L[k] - m);

    float p0 = rois[n * 4 + 0], p1 = rois[n * 4 + 1];
    float p2 = rois[n * 4 + 2], p3 = rois[n * 4 + 3];
    float w = p2 - p0, h = p3 - p1;
    float cx = p0 + 0.5f * w, cy = p1 + 0.5f * h;

    for (int k = 1; k < NCLS; ++k) {
        int i = n * 20 + (k - 1);
        float s = expf(L[k] - m) / sum;
        const float* D = L + NCLS + k * 4;
        float dx = D[0], dy = D[1], dw = D[2], dh = D[3];
        float pcx = dx * w + cx;
        float pcy = dy * h + cy;
        float pw = expf(dw) * w;
        float ph = expf(dh) * h;
        float b0 = pcx - 0.5f * pw;
        float b1 = pcy - 0.5f * ph;
        float b2 = pcx + 0.5f * pw;
        float b3 = pcy + 0.5f * ph;
        boxes[(size_t)i * 4 + 0] = b0;
        boxes[(size_t)i * 4 + 1] = b1;
        boxes[(size_t)i * 4 + 2] = b2;
        boxes[(size_t)i * 4 + 3] = b3;
        cand[i] = (s > SCORE_T) ? s : -__builtin_inff();
        float offv = (float)k * 10000.0f;   // label = k, same f32 ops as reference
        ((float4*)boxesT)[(k - 1) * 1024 + n] =
            make_float4(b0 + offv, b1 + offv, b2 + offv, b3 + offv);
    }
}

// ---------------- per-class NMS: sort + suppression bitmask + single-wave scan ----------------
// Equivalence to the reference global loop: cross-class IoU is exactly 0 (class offsets
// are 10000 apart, boxes span <~1000), so suppression is class-local; the global pick
// sequence is the score-desc merge of per-class greedy-NMS survivor lists. Keys
// (score_bits<<32)|~idx preserve exact scores and jnp.argmax first-max tie-break.
__global__ __launch_bounds__(256) void k_nms_cls(const float* __restrict__ cand,
                                                 const float* __restrict__ boxesT,
                                                 unsigned long long* __restrict__ maskws,
                                                 unsigned long long* __restrict__ accG,
                                                 int* __restrict__ accN) {
    __shared__ unsigned long long skeys[1024];
    __shared__ float4 bbox[1024];
    __shared__ unsigned long long accL[MAXDET];
    __shared__ int sV, sM;
    int tid = threadIdx.x;
    int c = blockIdx.x;            // class 0..19
    if (tid == 0) { sV = 0; sM = 0; }

    // load keys (invalid -> 0)
    for (int n = tid; n < 1024; n += 256) {
        unsigned long long key = 0ULL;
        if (n < NPROP) {
            float v = cand[n * 20 + c];
            if (v > 0.0f) {
                key = ((unsigned long long)__float_as_uint(v) << 32) |
                      (unsigned long long)(0xFFFFFFFFu - (unsigned)(n * 20 + c));
            }
        }
        skeys[n] = key;
    }
    __syncthreads();

    // bitonic sort, descending (zeros sink to the end)
    for (int k = 2; k <= 1024; k <<= 1) {
        for (int j = k >> 1; j > 0; j >>= 1) {
            for (int t = tid; t < 512; t += 256) {
                int i = ((t & ~(j - 1)) << 1) | (t & (j - 1));
                int l = i | j;
                unsigned long long a = skeys[i], b = skeys[l];
                bool up = (i & k) == 0;           // descending in up blocks
                if (up ? (a < b) : (a > b)) { skeys[i] = b; skeys[l] = a; }
            }
            __syncthreads();
        }
    }

    // count valid
    {
        int cnt = 0;
        for (int n = tid; n < 1024; n += 256)
            if (skeys[n] != 0ULL) ++cnt;
        if (cnt) atomicAdd(&sV, cnt);
    }
    __syncthreads();
    int V = sV;

    if (V > 0) {
        // gather sorted offset-boxes
        for (int r = tid; r < V; r += 256) {
            unsigned idx = 0xFFFFFFFFu - (unsigned)(skeys[r] & 0xFFFFFFFFu);
            int n = idx / 20;      // idx % 20 == c
            bbox[r] = ((const float4*)boxesT)[c * 1024 + n];
        }
        __syncthreads();

        // suppression bitmask rows (upper triangle): bit k of word w in row j set iff
        // IoU(box_j, box_k) > NMS_T with k > j. Bit-identical float ops to reference.
        int W = (V + 63) >> 6;
        unsigned long long* mrow = maskws + (size_t)c * 16384;
        for (int j = tid; j < V; j += 256) {
            float4 a = bbox[j];
            float qa = (a.z - a.x) * (a.w - a.y);
            for (int w = 0; w < W; ++w) {
                unsigned long long m = 0ULL;
                if (w >= (j >> 6)) {
                    #pragma unroll 4
                    for (int b = 0; b < 64; ++b) {
                        int kk = w * 64 + b;
                        if (kk > j && kk < V) {
                            float4 cb = bbox[kk];
                            float ix1 = fmaxf(a.x, cb.x), iy1 = fmaxf(a.y, cb.y);
                            float ix2 = fminf(a.z, cb.z), iy2 = fminf(a.w, cb.w);
                            float inter = fmaxf(ix2 - ix1, 0.f) * fmaxf(iy2 - iy1, 0.f);
                            float A2 = (cb.z - cb.x) * (cb.w - cb.y);
                            float iou = inter / (qa + A2 - inter + 1e-9f);
                            if (iou > NMS_T) m |= (1ULL << b);
                        }
                    }
                }
                mrow[j * 16 + w] = m;
            }
        }
        __syncthreads();

        // single-wave greedy scan with 1024-bit suppression set (lane w holds word w)
        if (tid < 64) {
            unsigned long long sup = 0ULL;
            int m = 0;
            for (int j = 0; j < V && m < MAXDET; ++j) {
                unsigned long long sw = __shfl(sup, j >> 6);
                if (!((sw >> (j & 63)) & 1ULL)) {
                    if (tid == 0) accL[m] = skeys[j];
                    if (tid < W) sup |= mrow[j * 16 + tid];
                    ++m;
                }
            }
            if (tid == 0) sM = m;
        }
    }
    __syncthreads();
    int m = sM;
    if (tid < m) accG[c * MAXDET + tid] = accL[tid];
    if (tid == 0) accN[c] = m;
}

// ---------------- merge: 20-way sorted merge by key, top-100, write outputs ----------------
__global__ __launch_bounds__(128) void k_nms_merge(const unsigned long long* __restrict__ accG,
                                                   const int* __restrict__ accN,
                                                   const float* __restrict__ boxes,
                                                   float* __restrict__ out) {
    __shared__ unsigned long long picks[MAXDET];
    int tid = threadIdx.x;
    if (tid < 64) {
        int c = tid;
        int cnt = (c < 20) ? accN[c] : 0;
        int ptr = 0;
        unsigned long long key = (cnt > 0) ? accG[c * MAXDET] : 0ULL;
        for (int it = 0; it < MAXDET; ++it) {
            unsigned long long k = key;
            #pragma unroll
            for (int off = 32; off > 0; off >>= 1) {
                unsigned long long o = __shfl_down(k, off);
                if (o > k) k = o;
            }
            unsigned long long g = __shfl(k, 0);
            if (tid == 0) picks[it] = g;
            if (g != 0ULL && key == g) {       // unique (idx embedded in key)
                ++ptr;
                key = (ptr < cnt) ? accG[c * MAXDET + ptr] : 0ULL;
            }
        }
    }
    __syncthreads();
    if (tid < MAXDET) {
        unsigned long long g = picks[tid];
        if (g != 0ULL) {
            int bi = (int)(0xFFFFFFFFu - (unsigned)(g & 0xFFFFFFFFu));
            float4 b = ((const float4*)boxes)[bi];
            out[tid * 4 + 0] = b.x; out[tid * 4 + 1] = b.y;
            out[tid * 4 + 2] = b.z; out[tid * 4 + 3] = b.w;
            out[400 + tid] = __uint_as_float((unsigned)(g >> 32));
            out[500 + tid] = (float)(bi - (bi / 20) * 20 + 1);
        } else {
            out[tid * 4 + 0] = 0.f; out[tid * 4 + 1] = 0.f;
            out[tid * 4 + 2] = 0.f; out[tid * 4 + 3] = 0.f;
            out[400 + tid] = 0.f;
            out[500 + tid] = 0.f;
        }
    }
}

extern "C" void kernel_launch(void* const* d_in, const int* in_sizes, int n_in,
                              void* d_out, int out_size, void* d_ws, size_t ws_size,
                              hipStream_t stream) {
    const float* fm   = (const float*)d_in[0];
    const float* rois = (const float*)d_in[1];
    const float* w1   = (const float*)d_in[2];
    const float* b1   = (const float*)d_in[3];
    const float* w2   = (const float*)d_in[4];
    const float* b2   = (const float*)d_in[5];
    const float* wc   = (const float*)d_in[6];
    const float* bc   = (const float*)d_in[7];
    const float* wb   = (const float*)d_in[8];
    const float* bb   = (const float*)d_in[9];
    float* out = (float*)d_out;

    float* ws = (float*)d_ws;
    float* fmT    = ws;                       // 2,560,000 floats (reused as P after roi)
    float* P      = ws;                       // 2 x 1,048,576 partials (GEMM split-K)
    float* pooled = fmT + 2560000;            // 12,544,000 (reused after GEMM1:)
    float* x1     = pooled + 12544000;        // 1,024,000
    float* x2     = x1 + 1024000;             // 1,024,000
    float* logits = x2 + 1024000;             // 105,000
    float* boxes  = logits + 105000;          // 80,000
    float* cand   = boxes + 80000;            // 20,000
    // reuse of pooled region (GEMM1 consumed it before k_prep):
    float* boxesT = pooled;                                   // 81,920 floats
    unsigned long long* maskws = (unsigned long long*)(pooled + 131072);  // 327,680 u64
    unsigned long long* accG   = (unsigned long long*)(pooled + 786432);  // 2,000 u64
    int* accN                  = (int*)(pooled + 790432);                 // 20 ints

    k_transpose<<<157, 256, 0, stream>>>(fm, fmT);
    k_roi<<<NPROP, 256, 0, stream>>>(fmT, rois, pooled);
    k_gemm_mfma<<<dim3(16, 16, 2), 256, 0, stream>>>(pooled, w1, P, NPROP, FEAT, 196);
    k_fuse<<<1000, 256, 0, stream>>>(P, b1, x1);
    k_gemm_mfma<<<dim3(16, 16, 2), 256, 0, stream>>>(x1, w2, P, NPROP, HID, 16);
    k_fuse<<<1000, 256, 0, stream>>>(P, b2, x2);
    k_heads<<<250, 128, 0, stream>>>(x2, wc, bc, wb, bb, logits);
    k_prep<<<4, 256, 0, stream>>>(logits, rois, boxes, cand, boxesT);
    k_nms_cls<<<20, 256, 0, stream>>>(cand, boxesT, maskws, accG, accN);
    k_nms_merge<<<1, 128, 0, stream>>>(accG, accN, boxes, out);
}

// Round 7
// 745.483 us; speedup vs baseline: 1.3151x; 1.3151x over previous
//
#include <hip/hip_runtime.h>
#include <math.h>

#define NPROP 1000
#define CCH 256
#define FH 100
#define FW 100
#define POOLSZ 7
#define FEAT 12544   // 256*49
#define HID 1024
#define NCLS 21
#define NHEAD 105    // 21 + 84
#define NCAND 20000  // 1000 * 20
#define SCORE_T 0.05f
#define NMS_T 0.5f
#define MAXDET 100

typedef _Float16 f16;
typedef __attribute__((ext_vector_type(8))) _Float16 f16x8;
typedef __attribute__((ext_vector_type(4))) float f32x4;

// ---------------- transpose fm [256,100,100] -> fmT [100*100, 256] ----------------
__global__ __launch_bounds__(256) void k_transpose(const float* __restrict__ fm,
                                                   float* __restrict__ fmT) {
    __shared__ float lds[64 * 257];
    int posbase = blockIdx.x * 64;
    int tid = threadIdx.x;
    int cq = tid >> 6;   // 0..3
    int pl = tid & 63;   // 0..63
    int pos = posbase + pl;
    bool pok = pos < FH * FW;
    for (int c0 = 0; c0 < CCH; c0 += 4) {
        int c = c0 + cq;
        float v = pok ? fm[c * (FH * FW) + pos] : 0.f;
        lds[pl * 257 + c] = v;
    }
    __syncthreads();
    for (int p = 0; p < 64; ++p) {
        int pos2 = posbase + p;
        if (pos2 < FH * FW) fmT[(size_t)pos2 * CCH + tid] = lds[p * 257 + tid];
    }
}

// ---------------- ROI align: pooled [1000][12544], k = c*49 + py*7 + px ----------------
__global__ __launch_bounds__(256) void k_roi(const float* __restrict__ fmT,
                                             const float* __restrict__ rois,
                                             float* __restrict__ pooled) {
    int n = blockIdx.x;
    int tid = threadIdx.x;
    __shared__ float wx0[14], wx1[14], wy0[14], wy1[14];
    __shared__ int ix0[14], ix1[14], iy0[14], iy1[14], vx[14], vy[14];
    __shared__ float outb[FEAT];

    if (tid < 28) {
        int axis = tid / 14;  // 0=x, 1=y
        int j = tid % 14;
        float p0 = rois[n * 4 + axis];
        float p1 = rois[n * 4 + 2 + axis];
        float b0 = p0 * 0.125f - 0.5f;
        float b1 = p1 * 0.125f - 0.5f;
        float bsz = (b1 - b0) / 7.0f;
        int p = j >> 1, s = j & 1;
        float off = (float)p + ((float)s + 0.5f) / 2.0f;
        float v = b0 + off * bsz;
        float size = 100.0f;
        int valid = (v >= -1.0f && v <= size) ? 1 : 0;
        v = fminf(fmaxf(v, 0.0f), size - 1.0f);
        float v0 = floorf(v);
        int i0 = (int)v0;
        int i1 = min(i0 + 1, 99);
        float w1v = v - v0;
        float w0v = 1.0f - w1v;
        if (axis == 0) { ix0[j] = i0 * CCH; ix1[j] = i1 * CCH; wx0[j] = w0v; wx1[j] = w1v; vx[j] = valid; }
        else           { iy0[j] = i0 * (FW * CCH); iy1[j] = i1 * (FW * CCH); wy0[j] = w0v; wy1[j] = w1v; vy[j] = valid; }
    }
    __syncthreads();

    int c = tid;
    for (int py = 0; py < POOLSZ; ++py) {
        for (int px = 0; px < POOLSZ; ++px) {
            float acc = 0.f;
            #pragma unroll
            for (int sy = 0; sy < 2; ++sy) {
                int jy = py * 2 + sy;
                if (!vy[jy]) continue;
                float fy0 = wy0[jy], fy1 = wy1[jy];
                int y0 = iy0[jy], y1 = iy1[jy];
                #pragma unroll
                for (int sx = 0; sx < 2; ++sx) {
                    int jx = px * 2 + sx;
                    if (!vx[jx]) continue;
                    float fx0 = wx0[jx], fx1 = wx1[jx];
                    int x0 = ix0[jx], x1 = ix1[jx];
                    float a00 = fmT[y0 + x0 + c];
                    float a01 = fmT[y0 + x1 + c];
                    float a10 = fmT[y1 + x0 + c];
                    float a11 = fmT[y1 + x1 + c];
                    acc += fy0 * (fx0 * a00 + fx1 * a01) + fy1 * (fx0 * a10 + fx1 * a11);
                }
            }
            outb[c * 49 + py * 7 + px] = acc * 0.25f;
        }
    }
    __syncthreads();
    size_t base = (size_t)n * FEAT;
    for (int o = tid; o < FEAT; o += 256)
        pooled[base + o] = outb[o];
}

// ---------------- MFMA GEMM, f16 3-pass split (fp32-class accuracy) ----------------
__global__ __launch_bounds__(256) void k_gemm_mfma(const float* __restrict__ A,
                                                   const float* __restrict__ B,
                                                   float* __restrict__ P,
                                                   int M, int K, int nt) {
    __shared__ f16 Ah[2][2048], Al[2][2048], Bh[2][2048], Bl[2][2048];
    int tid = threadIdx.x;
    int n0 = blockIdx.x * 64;
    int m0 = blockIdx.y * 64;
    int kz = blockIdx.z;
    int kbase0 = kz * nt * 32;

    int a_row = tid >> 2;   // 0..63
    int a_kq  = tid & 3;    // 0..3 (8 k's each)
    int b_n   = tid & 63;
    int b_kg  = tid >> 6;   // == wave id

    int wave = tid >> 6, lane = tid & 63;
    int wr = (wave >> 1) * 32, wc = (wave & 1) * 32;
    int lhi = lane >> 4, llo = lane & 15;

    f32x4 accm[2][2] = {};
    f32x4 accc[2][2] = {};

    float aS[8], bS[8];
    const float* Arow = A + (size_t)(m0 + a_row) * K;
    bool arow_ok = (m0 + a_row) < M;

    int a_st = a_kq * 512 + ((a_row ^ a_kq) << 3);
    int b_st = b_kg * 512 + (b_n << 3);
    int a_rd0 = lhi * 512 + (((wr + 0  + llo) ^ lhi) << 3);
    int a_rd1 = lhi * 512 + (((wr + 16 + llo) ^ lhi) << 3);
    int b_rd0 = lhi * 512 + ((wc + 0  + llo) << 3);
    int b_rd1 = lhi * 512 + ((wc + 16 + llo) << 3);

    auto LOAD = [&](int t) {
        int kb = kbase0 + t * 32;
        if (arow_ok) {
            const float* ap = Arow + kb + a_kq * 8;
            float4 v0 = *(const float4*)(ap);
            float4 v1 = *(const float4*)(ap + 4);
            aS[0] = v0.x; aS[1] = v0.y; aS[2] = v0.z; aS[3] = v0.w;
            aS[4] = v1.x; aS[5] = v1.y; aS[6] = v1.z; aS[7] = v1.w;
        } else {
            #pragma unroll
            for (int j = 0; j < 8; ++j) aS[j] = 0.f;
        }
        const float* bp = B + (size_t)(kb + b_kg * 8) * 1024 + n0 + b_n;
        #pragma unroll
        for (int j = 0; j < 8; ++j) bS[j] = bp[(size_t)j * 1024];
    };
    auto STORE = [&](int buf) {
        f16x8 vh, vl;
        #pragma unroll
        for (int j = 0; j < 8; ++j) {
            f16 h = (f16)aS[j];
            vh[j] = h;
            vl[j] = (f16)((aS[j] - (float)h) * 4096.0f);
        }
        *(f16x8*)&Ah[buf][a_st] = vh;
        *(f16x8*)&Al[buf][a_st] = vl;
        #pragma unroll
        for (int j = 0; j < 8; ++j) {
            f16 h = (f16)bS[j];
            vh[j] = h;
            vl[j] = (f16)((bS[j] - (float)h) * 4096.0f);
        }
        *(f16x8*)&Bh[buf][b_st] = vh;
        *(f16x8*)&Bl[buf][b_st] = vl;
    };

    LOAD(0);
    STORE(0);
    __syncthreads();

    for (int t = 0; t < nt; ++t) {
        int cur = t & 1;
        if (t + 1 < nt) LOAD(t + 1);
        {
            f16x8 ah0 = *(f16x8*)&Ah[cur][a_rd0];
            f16x8 ah1 = *(f16x8*)&Ah[cur][a_rd1];
            f16x8 bh0 = *(f16x8*)&Bh[cur][b_rd0];
            f16x8 bh1 = *(f16x8*)&Bh[cur][b_rd1];
            f16x8 al0 = *(f16x8*)&Al[cur][a_rd0];
            f16x8 al1 = *(f16x8*)&Al[cur][a_rd1];
            f16x8 bl0 = *(f16x8*)&Bl[cur][b_rd0];
            f16x8 bl1 = *(f16x8*)&Bl[cur][b_rd1];
            accm[0][0] = __builtin_amdgcn_mfma_f32_16x16x32_f16(ah0, bh0, accm[0][0], 0, 0, 0);
            accm[0][1] = __builtin_amdgcn_mfma_f32_16x16x32_f16(ah0, bh1, accm[0][1], 0, 0, 0);
            accm[1][0] = __builtin_amdgcn_mfma_f32_16x16x32_f16(ah1, bh0, accm[1][0], 0, 0, 0);
            accm[1][1] = __builtin_amdgcn_mfma_f32_16x16x32_f16(ah1, bh1, accm[1][1], 0, 0, 0);
            accc[0][0] = __builtin_amdgcn_mfma_f32_16x16x32_f16(ah0, bl0, accc[0][0], 0, 0, 0);
            accc[0][1] = __builtin_amdgcn_mfma_f32_16x16x32_f16(ah0, bl1, accc[0][1], 0, 0, 0);
            accc[1][0] = __builtin_amdgcn_mfma_f32_16x16x32_f16(ah1, bl0, accc[1][0], 0, 0, 0);
            accc[1][1] = __builtin_amdgcn_mfma_f32_16x16x32_f16(ah1, bl1, accc[1][1], 0, 0, 0);
            accc[0][0] = __builtin_amdgcn_mfma_f32_16x16x32_f16(al0, bh0, accc[0][0], 0, 0, 0);
            accc[0][1] = __builtin_amdgcn_mfma_f32_16x16x32_f16(al0, bh1, accc[0][1], 0, 0, 0);
            accc[1][0] = __builtin_amdgcn_mfma_f32_16x16x32_f16(al1, bh0, accc[1][0], 0, 0, 0);
            accc[1][1] = __builtin_amdgcn_mfma_f32_16x16x32_f16(al1, bh1, accc[1][1], 0, 0, 0);
        }
        if (t + 1 < nt) {
            STORE(cur ^ 1);
            __syncthreads();
        }
    }

    const float inv = 1.0f / 4096.0f;
    #pragma unroll
    for (int mi = 0; mi < 2; ++mi) {
        #pragma unroll
        for (int r = 0; r < 4; ++r) {
            int row = m0 + wr + mi * 16 + lhi * 4 + r;
            if (row < M) {
                #pragma unroll
                for (int ni = 0; ni < 2; ++ni) {
                    int col = n0 + wc + ni * 16 + llo;
                    float v = accm[mi][ni][r] + accc[mi][ni][r] * inv;
                    P[(size_t)kz * 1048576 + (size_t)row * 1024 + col] = v;
                }
            }
        }
    }
}

// ---------------- fuse: out = relu(P0 + P1 + bias), 1000x1024 ----------------
__global__ __launch_bounds__(256) void k_fuse(const float* __restrict__ P,
                                              const float* __restrict__ bias,
                                              float* __restrict__ out) {
    int t = blockIdx.x * 256 + threadIdx.x;   // float4 index, 0..255999
    float4 p0 = ((const float4*)P)[t];
    float4 p1 = ((const float4*)(P + 1048576))[t];
    float4 b  = ((const float4*)bias)[t & 255];
    float4 v;
    v.x = fmaxf(p0.x + p1.x + b.x, 0.f);
    v.y = fmaxf(p0.y + p1.y + b.y, 0.f);
    v.z = fmaxf(p0.z + p1.z + b.z, 0.f);
    v.w = fmaxf(p0.w + p1.w + b.w, 0.f);
    ((float4*)out)[t] = v;
}

// ---------------- heads: logits[1000][105] = x2 @ [wc|wb] + [bc|bb] ----------------
__global__ __launch_bounds__(128) void k_heads(const float* __restrict__ x2,
                                               const float* __restrict__ wc,
                                               const float* __restrict__ bc,
                                               const float* __restrict__ wb,
                                               const float* __restrict__ bb,
                                               float* __restrict__ logits) {
    int r0 = blockIdx.x * 4;
    __shared__ float xs[4][HID];
    for (int i = threadIdx.x; i < 4 * HID; i += 128) {
        int rr = i >> 10, kk = i & 1023;
        xs[rr][kk] = x2[(size_t)(r0 + rr) * HID + kk];
    }
    __syncthreads();
    int j = threadIdx.x;
    if (j < NHEAD) {
        float a0 = 0.f, a1 = 0.f, a2 = 0.f, a3 = 0.f;
        if (j < NCLS) {
            for (int k = 0; k < HID; ++k) {
                float w = wc[k * NCLS + j];
                a0 = fmaf(xs[0][k], w, a0);
                a1 = fmaf(xs[1][k], w, a1);
                a2 = fmaf(xs[2][k], w, a2);
                a3 = fmaf(xs[3][k], w, a3);
            }
            float b = bc[j];
            a0 += b; a1 += b; a2 += b; a3 += b;
        } else {
            int jb = j - NCLS;
            for (int k = 0; k < HID; ++k) {
                float w = wb[k * 84 + jb];
                a0 = fmaf(xs[0][k], w, a0);
                a1 = fmaf(xs[1][k], w, a1);
                a2 = fmaf(xs[2][k], w, a2);
                a3 = fmaf(xs[3][k], w, a3);
            }
            float b = bb[jb];
            a0 += b; a1 += b; a2 += b; a3 += b;
        }
        logits[(size_t)(r0 + 0) * NHEAD + j] = a0;
        logits[(size_t)(r0 + 1) * NHEAD + j] = a1;
        logits[(size_t)(r0 + 2) * NHEAD + j] = a2;
        logits[(size_t)(r0 + 3) * NHEAD + j] = a3;
    }
}

// ---------------- softmax + decode + candidates + class-major offset boxes ----------------
__global__ __launch_bounds__(256) void k_prep(const float* __restrict__ logits,
                                              const float* __restrict__ rois,
                                              float* __restrict__ boxes,
                                              float* __restrict__ cand,
                                              float* __restrict__ boxesT) {
    int n = blockIdx.x * 256 + threadIdx.x;
    if (n >= NPROP) return;
    const float* L = logits + (size_t)n * NHEAD;
    float m = L[0];
    #pragma unroll
    for (int k = 1; k < NCLS; ++k) m = fmaxf(m, L[k]);
    float sum = 0.f;
    #pragma unroll
    for (int k = 0; k < NCLS; ++k) sum += expf(L[k] - m);

    float p0 = rois[n * 4 + 0], p1 = rois[n * 4 + 1];
    float p2 = rois[n * 4 + 2], p3 = rois[n * 4 + 3];
    float w = p2 - p0, h = p3 - p1;
    float cx = p0 + 0.5f * w, cy = p1 + 0.5f * h;

    for (int k = 1; k < NCLS; ++k) {
        int i = n * 20 + (k - 1);
        float s = expf(L[k] - m) / sum;
        const float* D = L + NCLS + k * 4;
        float dx = D[0], dy = D[1], dw = D[2], dh = D[3];
        float pcx = dx * w + cx;
        float pcy = dy * h + cy;
        float pw = expf(dw) * w;
        float ph = expf(dh) * h;
        float b0 = pcx - 0.5f * pw;
        float b1 = pcy - 0.5f * ph;
        float b2 = pcx + 0.5f * pw;
        float b3 = pcy + 0.5f * ph;
        boxes[(size_t)i * 4 + 0] = b0;
        boxes[(size_t)i * 4 + 1] = b1;
        boxes[(size_t)i * 4 + 2] = b2;
        boxes[(size_t)i * 4 + 3] = b3;
        cand[i] = (s > SCORE_T) ? s : -__builtin_inff();
        float offv = (float)k * 10000.0f;   // label = k, same f32 ops as reference
        ((float4*)boxesT)[(k - 1) * 1024 + n] =
            make_float4(b0 + offv, b1 + offv, b2 + offv, b3 + offv);
    }
}

// ---------------- per-class NMS: greedy in registers, 20 concurrent blocks ----------------
// Equivalence to the reference global loop: cross-class IoU is exactly 0 (class offsets
// are 10000 apart, boxes span <~1000), so suppression is class-local; the global pick
// sequence is the score-desc merge of per-class greedy-NMS survivor lists. Keys
// (score_bits<<32)|~idx preserve exact scores and jnp.argmax first-max tie-break.
// Each thread owns 4 proposals (n = tid + 256*r) of its class: scores + offset boxes
// entirely in registers -> suppress phase is 4 register IoUs, no LDS/global traffic.
__global__ __launch_bounds__(256) void k_nms_cls(const float* __restrict__ cand,
                                                 const float* __restrict__ boxesT,
                                                 unsigned long long* __restrict__ accG,
                                                 int* __restrict__ accN) {
    __shared__ unsigned long long gkeys[2];      // ping-pong argmax
    __shared__ unsigned long long accL[MAXDET];  // picked keys
    __shared__ float sb4[4];                     // winner offset box broadcast
    __shared__ int sM;
    int tid = threadIdx.x;
    int c = blockIdx.x;   // class 0..19
    if (tid == 0) { gkeys[0] = 0ULL; gkeys[1] = 0ULL; sM = MAXDET; }

    float s[4];
    float4 bx[4];
    #pragma unroll
    for (int r = 0; r < 4; ++r) {
        int n = tid + (r << 8);
        if (n < NPROP) {
            s[r] = cand[n * 20 + c];
            bx[r] = ((const float4*)boxesT)[c * 1024 + n];
        } else {
            s[r] = -__builtin_inff();
            bx[r] = make_float4(0.f, 0.f, 0.f, 0.f);
        }
    }
    __syncthreads();

    for (int it = 0; it < MAXDET; ++it) {
        int cur = it & 1;
        unsigned long long k = 0ULL;
        #pragma unroll
        for (int r = 0; r < 4; ++r) {
            if (s[r] > 0.0f) {
                int n = tid + (r << 8);
                unsigned long long kk =
                    ((unsigned long long)__float_as_uint(s[r]) << 32) |
                    (unsigned long long)(0xFFFFFFFFu - (unsigned)(n * 20 + c));
                if (kk > k) k = kk;
            }
        }
        #pragma unroll
        for (int off = 32; off > 0; off >>= 1) {
            unsigned long long o = __shfl_down(k, off);
            if (o > k) k = o;
        }
        if ((tid & 63) == 0) atomicMax(&gkeys[cur], k);
        __syncthreads();   // A: argmax done
        unsigned long long g = gkeys[cur];
        if (tid == 0) {
            gkeys[cur ^ 1] = 0ULL;
            accL[it] = g;
            if (g == 0ULL) sM = it;
        }
        if (g != 0ULL) {
            int n_win = (int)(0xFFFFFFFFu - (unsigned)(g & 0xFFFFFFFFu)) / 20;
            if ((n_win & 255) == tid) {
                float4 b = bx[n_win >> 8];
                sb4[0] = b.x; sb4[1] = b.y; sb4[2] = b.z; sb4[3] = b.w;
            }
        }
        __syncthreads();   // B: sb4 + resets + sM visible
        if (g == 0ULL) break;  // uniform across block

        float q0 = sb4[0], q1 = sb4[1], q2 = sb4[2], q3 = sb4[3];
        float qa = (q2 - q0) * (q3 - q1);
        #pragma unroll
        for (int r = 0; r < 4; ++r) {
            if (s[r] > 0.0f) {
                float4 cb = bx[r];
                float ix1 = fmaxf(q0, cb.x), iy1 = fmaxf(q1, cb.y);
                float ix2 = fminf(q2, cb.z), iy2 = fminf(q3, cb.w);
                float inter = fmaxf(ix2 - ix1, 0.f) * fmaxf(iy2 - iy1, 0.f);
                float A2 = (cb.z - cb.x) * (cb.w - cb.y);
                float iou = inter / (qa + A2 - inter + 1e-9f);
                if (iou > NMS_T) s[r] = -__builtin_inff();
            }
        }
    }

    __syncthreads();
    int mm = sM;
    if (tid < mm) accG[c * MAXDET + tid] = accL[tid];
    if (tid == 0) accN[c] = mm;
}

// ---------------- merge: 20-way sorted merge by key, top-100, write outputs ----------------
__global__ __launch_bounds__(128) void k_nms_merge(const unsigned long long* __restrict__ accG,
                                                   const int* __restrict__ accN,
                                                   const float* __restrict__ boxes,
                                                   float* __restrict__ out) {
    __shared__ unsigned long long picks[MAXDET];
    int tid = threadIdx.x;
    if (tid < 64) {
        int c = tid;
        int cnt = (c < 20) ? accN[c] : 0;
        int ptr = 0;
        unsigned long long key = (cnt > 0) ? accG[c * MAXDET] : 0ULL;
        for (int it = 0; it < MAXDET; ++it) {
            unsigned long long k = key;
            #pragma unroll
            for (int off = 32; off > 0; off >>= 1) {
                unsigned long long o = __shfl_down(k, off);
                if (o > k) k = o;
            }
            unsigned long long g = __shfl(k, 0);
            if (tid == 0) picks[it] = g;
            if (g != 0ULL && key == g) {       // unique (idx embedded in key)
                ++ptr;
                key = (ptr < cnt) ? accG[c * MAXDET + ptr] : 0ULL;
            }
        }
    }
    __syncthreads();
    if (tid < MAXDET) {
        unsigned long long g = picks[tid];
        if (g != 0ULL) {
            int bi = (int)(0xFFFFFFFFu - (unsigned)(g & 0xFFFFFFFFu));
            float4 b = ((const float4*)boxes)[bi];
            out[tid * 4 + 0] = b.x; out[tid * 4 + 1] = b.y;
            out[tid * 4 + 2] = b.z; out[tid * 4 + 3] = b.w;
            out[400 + tid] = __uint_as_float((unsigned)(g >> 32));
            out[500 + tid] = (float)(bi - (bi / 20) * 20 + 1);
        } else {
            out[tid * 4 + 0] = 0.f; out[tid * 4 + 1] = 0.f;
            out[tid * 4 + 2] = 0.f; out[tid * 4 + 3] = 0.f;
            out[400 + tid] = 0.f;
            out[500 + tid] = 0.f;
        }
    }
}

extern "C" void kernel_launch(void* const* d_in, const int* in_sizes, int n_in,
                              void* d_out, int out_size, void* d_ws, size_t ws_size,
                              hipStream_t stream) {
    const float* fm   = (const float*)d_in[0];
    const float* rois = (const float*)d_in[1];
    const float* w1   = (const float*)d_in[2];
    const float* b1   = (const float*)d_in[3];
    const float* w2   = (const float*)d_in[4];
    const float* b2   = (const float*)d_in[5];
    const float* wc   = (const float*)d_in[6];
    const float* bc   = (const float*)d_in[7];
    const float* wb   = (const float*)d_in[8];
    const float* bb   = (const float*)d_in[9];
    float* out = (float*)d_out;

    float* ws = (float*)d_ws;
    float* fmT    = ws;                       // 2,560,000 floats (reused as P after roi)
    float* P      = ws;                       // 2 x 1,048,576 partials (GEMM split-K)
    float* pooled = fmT + 2560000;            // 12,544,000 (reused after GEMM1:)
    float* x1     = pooled + 12544000;        // 1,024,000
    float* x2     = x1 + 1024000;             // 1,024,000
    float* logits = x2 + 1024000;             // 105,000
    float* boxes  = logits + 105000;          // 80,000
    float* cand   = boxes + 80000;            // 20,000
    // reuse of pooled region (GEMM1 consumed it before k_prep):
    float* boxesT = pooled;                                   // 81,920 floats
    unsigned long long* accG   = (unsigned long long*)(pooled + 131072);  // 2,000 u64
    int* accN                  = (int*)(pooled + 135072);                 // 20 ints

    k_transpose<<<157, 256, 0, stream>>>(fm, fmT);
    k_roi<<<NPROP, 256, 0, stream>>>(fmT, rois, pooled);
    k_gemm_mfma<<<dim3(16, 16, 2), 256, 0, stream>>>(pooled, w1, P, NPROP, FEAT, 196);
    k_fuse<<<1000, 256, 0, stream>>>(P, b1, x1);
    k_gemm_mfma<<<dim3(16, 16, 2), 256, 0, stream>>>(x1, w2, P, NPROP, HID, 16);
    k_fuse<<<1000, 256, 0, stream>>>(P, b2, x2);
    k_heads<<<250, 128, 0, stream>>>(x2, wc, bc, wb, bb, logits);
    k_prep<<<4, 256, 0, stream>>>(logits, rois, boxes, cand, boxesT);
    k_nms_cls<<<20, 256, 0, stream>>>(cand, boxesT, accG, accN);
    k_nms_merge<<<1, 128, 0, stream>>>(accG, accN, boxes, out);
}

// Round 8
// 683.655 us; speedup vs baseline: 1.4341x; 1.0904x over previous
//
#include <hip/hip_runtime.h>
#include <math.h>

#define NPROP 1000
#define CCH 256
#define FH 100
#define FW 100
#define POOLSZ 7
#define FEAT 12544   // 256*49
#define HID 1024
#define NCLS 21
#define NHEAD 105    // 21 + 84
#define NCAND 20000  // 1000 * 20
#define SCORE_T 0.05f
#define NMS_T 0.5f
#define MAXDET 100

typedef _Float16 f16;
typedef __attribute__((ext_vector_type(8))) _Float16 f16x8;
typedef __attribute__((ext_vector_type(4))) float f32x4;

// ---------------- transpose fm [256,100,100] -> fmT [100*100, 256] ----------------
__global__ __launch_bounds__(256) void k_transpose(const float* __restrict__ fm,
                                                   float* __restrict__ fmT) {
    __shared__ float lds[64 * 257];
    int posbase = blockIdx.x * 64;
    int tid = threadIdx.x;
    int cq = tid >> 6;   // 0..3
    int pl = tid & 63;   // 0..63
    int pos = posbase + pl;
    bool pok = pos < FH * FW;
    for (int c0 = 0; c0 < CCH; c0 += 4) {
        int c = c0 + cq;
        float v = pok ? fm[c * (FH * FW) + pos] : 0.f;
        lds[pl * 257 + c] = v;
    }
    __syncthreads();
    for (int p = 0; p < 64; ++p) {
        int pos2 = posbase + p;
        if (pos2 < FH * FW) fmT[(size_t)pos2 * CCH + tid] = lds[p * 257 + tid];
    }
}

// ---------------- ROI align -> pooled in f16 hi/lo split, k = c*49 + py*7 + px ------
// Threads: cg = tid&63 (4 channels via float4), bo = tid>>6 (bins bo, bo+4, ...).
// Same float op order per element as the verified scalar version; h/l split identical
// to the previous in-GEMM split of the f32 pooled value (store->reload of f32 is exact).
__global__ __launch_bounds__(256) void k_roi(const float* __restrict__ fmT,
                                             const float* __restrict__ rois,
                                             f16* __restrict__ poolh,
                                             f16* __restrict__ pooll) {
    int n = blockIdx.x;
    int tid = threadIdx.x;
    __shared__ float wx0[14], wx1[14], wy0[14], wy1[14];
    __shared__ int ix0[14], ix1[14], iy0[14], iy1[14], vx[14], vy[14];  // float4 units
    __shared__ float outb[FEAT];

    if (tid < 28) {
        int axis = tid / 14;  // 0=x, 1=y
        int j = tid % 14;
        float p0 = rois[n * 4 + axis];
        float p1 = rois[n * 4 + 2 + axis];
        float b0 = p0 * 0.125f - 0.5f;
        float b1 = p1 * 0.125f - 0.5f;
        float bsz = (b1 - b0) / 7.0f;
        int p = j >> 1, s = j & 1;
        float off = (float)p + ((float)s + 0.5f) / 2.0f;
        float v = b0 + off * bsz;
        float size = 100.0f;
        int valid = (v >= -1.0f && v <= size) ? 1 : 0;
        v = fminf(fmaxf(v, 0.0f), size - 1.0f);
        float v0 = floorf(v);
        int i0 = (int)v0;
        int i1 = min(i0 + 1, 99);
        float w1v = v - v0;
        float w0v = 1.0f - w1v;
        if (axis == 0) { ix0[j] = i0 * 64; ix1[j] = i1 * 64; wx0[j] = w0v; wx1[j] = w1v; vx[j] = valid; }
        else           { iy0[j] = i0 * 6400; iy1[j] = i1 * 6400; wy0[j] = w0v; wy1[j] = w1v; vy[j] = valid; }
    }
    __syncthreads();

    int cg = tid & 63;   // channel group: channels 4cg..4cg+3
    int bo = tid >> 6;   // bin offset 0..3
    const float4* fm4 = (const float4*)fmT;
    for (int bin = bo; bin < 49; bin += 4) {
        int py = bin / 7;
        int px = bin - py * 7;
        float ax = 0.f, ay = 0.f, az = 0.f, aw = 0.f;
        #pragma unroll
        for (int sy = 0; sy < 2; ++sy) {
            int jy = py * 2 + sy;
            if (!vy[jy]) continue;
            float fy0 = wy0[jy], fy1 = wy1[jy];
            int y0 = iy0[jy], y1 = iy1[jy];
            #pragma unroll
            for (int sx = 0; sx < 2; ++sx) {
                int jx = px * 2 + sx;
                if (!vx[jx]) continue;
                float fx0 = wx0[jx], fx1 = wx1[jx];
                int x0 = ix0[jx], x1 = ix1[jx];
                float4 a00 = fm4[y0 + x0 + cg];
                float4 a01 = fm4[y0 + x1 + cg];
                float4 a10 = fm4[y1 + x0 + cg];
                float4 a11 = fm4[y1 + x1 + cg];
                ax += fy0 * (fx0 * a00.x + fx1 * a01.x) + fy1 * (fx0 * a10.x + fx1 * a11.x);
                ay += fy0 * (fx0 * a00.y + fx1 * a01.y) + fy1 * (fx0 * a10.y + fx1 * a11.y);
                az += fy0 * (fx0 * a00.z + fx1 * a01.z) + fy1 * (fx0 * a10.z + fx1 * a11.z);
                aw += fy0 * (fx0 * a00.w + fx1 * a01.w) + fy1 * (fx0 * a10.w + fx1 * a11.w);
            }
        }
        int c4 = cg * 4;
        outb[(c4 + 0) * 49 + bin] = ax * 0.25f;
        outb[(c4 + 1) * 49 + bin] = ay * 0.25f;
        outb[(c4 + 2) * 49 + bin] = az * 0.25f;
        outb[(c4 + 3) * 49 + bin] = aw * 0.25f;
    }
    __syncthreads();

    // pack f32 -> (h, l) f16 pairs, coalesced u32 writes
    unsigned* ph = (unsigned*)poolh + (size_t)n * 6272;
    unsigned* pl = (unsigned*)pooll + (size_t)n * 6272;
    for (int op = tid; op < 6272; op += 256) {
        float v0 = outb[2 * op];
        float v1 = outb[2 * op + 1];
        f16 h0 = (f16)v0;
        f16 l0 = (f16)((v0 - (float)h0) * 4096.0f);
        f16 h1 = (f16)v1;
        f16 l1 = (f16)((v1 - (float)h1) * 4096.0f);
        unsigned hu = (unsigned)__builtin_bit_cast(unsigned short, h0) |
                      ((unsigned)__builtin_bit_cast(unsigned short, h1) << 16);
        unsigned lu = (unsigned)__builtin_bit_cast(unsigned short, l0) |
                      ((unsigned)__builtin_bit_cast(unsigned short, l1) << 16);
        ph[op] = hu;
        pl[op] = lu;
    }
}

// ---------------- MFMA GEMM: A pre-split f16 (h/l), B f32 in-kernel split ----------
__global__ __launch_bounds__(256) void k_gemm_mfma(const f16* __restrict__ Ahg,
                                                   const f16* __restrict__ Alg,
                                                   const float* __restrict__ B,
                                                   float* __restrict__ P,
                                                   int M, int K, int nt) {
    __shared__ f16 Ah[2][2048], Al[2][2048], Bh[2][2048], Bl[2][2048];
    int tid = threadIdx.x;
    int n0 = blockIdx.x * 64;
    int m0 = blockIdx.y * 64;
    int kz = blockIdx.z;
    int kbase0 = kz * nt * 32;

    int a_row = tid >> 2;   // 0..63
    int a_kq  = tid & 3;    // 0..3 (8 k's each)
    int b_n   = tid & 63;
    int b_kg  = tid >> 6;   // == wave id

    int wave = tid >> 6, lane = tid & 63;
    int wr = (wave >> 1) * 32, wc = (wave & 1) * 32;
    int lhi = lane >> 4, llo = lane & 15;

    f32x4 accm[2][2] = {};
    f32x4 accc[2][2] = {};

    const f16x8 ZERO = {};
    f16x8 aH = ZERO, aL = ZERO;
    float bS[8];
    bool arow_ok = (m0 + a_row) < M;
    const f16* ArowH = Ahg + (size_t)(m0 + a_row) * K;
    const f16* ArowL = Alg + (size_t)(m0 + a_row) * K;

    int a_st = a_kq * 512 + ((a_row ^ a_kq) << 3);
    int b_st = b_kg * 512 + (b_n << 3);
    int a_rd0 = lhi * 512 + (((wr + 0  + llo) ^ lhi) << 3);
    int a_rd1 = lhi * 512 + (((wr + 16 + llo) ^ lhi) << 3);
    int b_rd0 = lhi * 512 + ((wc + 0  + llo) << 3);
    int b_rd1 = lhi * 512 + ((wc + 16 + llo) << 3);

    auto LOAD = [&](int t) {
        int kb = kbase0 + t * 32;
        if (arow_ok) {
            aH = *(const f16x8*)(ArowH + kb + a_kq * 8);
            aL = *(const f16x8*)(ArowL + kb + a_kq * 8);
        } else {
            aH = ZERO; aL = ZERO;
        }
        const float* bp = B + (size_t)(kb + b_kg * 8) * 1024 + n0 + b_n;
        #pragma unroll
        for (int j = 0; j < 8; ++j) bS[j] = bp[(size_t)j * 1024];
    };
    auto STORE = [&](int buf) {
        *(f16x8*)&Ah[buf][a_st] = aH;
        *(f16x8*)&Al[buf][a_st] = aL;
        f16x8 vh, vl;
        #pragma unroll
        for (int j = 0; j < 8; ++j) {
            f16 h = (f16)bS[j];
            vh[j] = h;
            vl[j] = (f16)((bS[j] - (float)h) * 4096.0f);
        }
        *(f16x8*)&Bh[buf][b_st] = vh;
        *(f16x8*)&Bl[buf][b_st] = vl;
    };

    LOAD(0);
    STORE(0);
    __syncthreads();

    for (int t = 0; t < nt; ++t) {
        int cur = t & 1;
        if (t + 1 < nt) LOAD(t + 1);
        {
            f16x8 ah0 = *(f16x8*)&Ah[cur][a_rd0];
            f16x8 ah1 = *(f16x8*)&Ah[cur][a_rd1];
            f16x8 bh0 = *(f16x8*)&Bh[cur][b_rd0];
            f16x8 bh1 = *(f16x8*)&Bh[cur][b_rd1];
            f16x8 al0 = *(f16x8*)&Al[cur][a_rd0];
            f16x8 al1 = *(f16x8*)&Al[cur][a_rd1];
            f16x8 bl0 = *(f16x8*)&Bl[cur][b_rd0];
            f16x8 bl1 = *(f16x8*)&Bl[cur][b_rd1];
            accm[0][0] = __builtin_amdgcn_mfma_f32_16x16x32_f16(ah0, bh0, accm[0][0], 0, 0, 0);
            accm[0][1] = __builtin_amdgcn_mfma_f32_16x16x32_f16(ah0, bh1, accm[0][1], 0, 0, 0);
            accm[1][0] = __builtin_amdgcn_mfma_f32_16x16x32_f16(ah1, bh0, accm[1][0], 0, 0, 0);
            accm[1][1] = __builtin_amdgcn_mfma_f32_16x16x32_f16(ah1, bh1, accm[1][1], 0, 0, 0);
            accc[0][0] = __builtin_amdgcn_mfma_f32_16x16x32_f16(ah0, bl0, accc[0][0], 0, 0, 0);
            accc[0][1] = __builtin_amdgcn_mfma_f32_16x16x32_f16(ah0, bl1, accc[0][1], 0, 0, 0);
            accc[1][0] = __builtin_amdgcn_mfma_f32_16x16x32_f16(ah1, bl0, accc[1][0], 0, 0, 0);
            accc[1][1] = __builtin_amdgcn_mfma_f32_16x16x32_f16(ah1, bl1, accc[1][1], 0, 0, 0);
            accc[0][0] = __builtin_amdgcn_mfma_f32_16x16x32_f16(al0, bh0, accc[0][0], 0, 0, 0);
            accc[0][1] = __builtin_amdgcn_mfma_f32_16x16x32_f16(al0, bh1, accc[0][1], 0, 0, 0);
            accc[1][0] = __builtin_amdgcn_mfma_f32_16x16x32_f16(al1, bh0, accc[1][0], 0, 0, 0);
            accc[1][1] = __builtin_amdgcn_mfma_f32_16x16x32_f16(al1, bh1, accc[1][1], 0, 0, 0);
        }
        if (t + 1 < nt) {
            STORE(cur ^ 1);
            __syncthreads();
        }
    }

    const float inv = 1.0f / 4096.0f;
    #pragma unroll
    for (int mi = 0; mi < 2; ++mi) {
        #pragma unroll
        for (int r = 0; r < 4; ++r) {
            int row = m0 + wr + mi * 16 + lhi * 4 + r;
            if (row < M) {
                #pragma unroll
                for (int ni = 0; ni < 2; ++ni) {
                    int col = n0 + wc + ni * 16 + llo;
                    float v = accm[mi][ni][r] + accc[mi][ni][r] * inv;
                    P[(size_t)kz * 1048576 + (size_t)row * 1024 + col] = v;
                }
            }
        }
    }
}

// ---------------- fuse f32: out = relu(P0 + P1 + bias), 1000x1024 -------------------
__global__ __launch_bounds__(256) void k_fuse_f32(const float* __restrict__ P,
                                                  const float* __restrict__ bias,
                                                  float* __restrict__ out) {
    int t = blockIdx.x * 256 + threadIdx.x;   // float4 index
    float4 p0 = ((const float4*)P)[t];
    float4 p1 = ((const float4*)(P + 1048576))[t];
    float4 b  = ((const float4*)bias)[t & 255];
    float4 v;
    v.x = fmaxf(p0.x + p1.x + b.x, 0.f);
    v.y = fmaxf(p0.y + p1.y + b.y, 0.f);
    v.z = fmaxf(p0.z + p1.z + b.z, 0.f);
    v.w = fmaxf(p0.w + p1.w + b.w, 0.f);
    ((float4*)out)[t] = v;
}

// ---------------- fuse f16: x1h/x1l = split(relu(P0 + P1 + bias)) -------------------
__global__ __launch_bounds__(256) void k_fuse_f16(const float* __restrict__ P,
                                                  const float* __restrict__ bias,
                                                  f16* __restrict__ oh,
                                                  f16* __restrict__ ol) {
    int t = blockIdx.x * 256 + threadIdx.x;
    float4 p0 = ((const float4*)P)[t];
    float4 p1 = ((const float4*)(P + 1048576))[t];
    float4 b  = ((const float4*)bias)[t & 255];
    float v[4];
    v[0] = fmaxf(p0.x + p1.x + b.x, 0.f);
    v[1] = fmaxf(p0.y + p1.y + b.y, 0.f);
    v[2] = fmaxf(p0.z + p1.z + b.z, 0.f);
    v[3] = fmaxf(p0.w + p1.w + b.w, 0.f);
    unsigned hu[4], lu[4];
    #pragma unroll
    for (int e = 0; e < 4; ++e) {
        f16 h = (f16)v[e];
        f16 l = (f16)((v[e] - (float)h) * 4096.0f);
        hu[e] = __builtin_bit_cast(unsigned short, h);
        lu[e] = __builtin_bit_cast(unsigned short, l);
    }
    uint2 hp, lp;
    hp.x = hu[0] | (hu[1] << 16); hp.y = hu[2] | (hu[3] << 16);
    lp.x = lu[0] | (lu[1] << 16); lp.y = lu[2] | (lu[3] << 16);
    ((uint2*)oh)[t] = hp;
    ((uint2*)ol)[t] = lp;
}

// ---------------- heads: logits[1000][105] = x2 @ [wc|wb] + [bc|bb] ----------------
__global__ __launch_bounds__(128) void k_heads(const float* __restrict__ x2,
                                               const float* __restrict__ wc,
                                               const float* __restrict__ bc,
                                               const float* __restrict__ wb,
                                               const float* __restrict__ bb,
                                               float* __restrict__ logits) {
    int r0 = blockIdx.x * 4;
    __shared__ float xs[4][HID];
    for (int i = threadIdx.x; i < 4 * HID; i += 128) {
        int rr = i >> 10, kk = i & 1023;
        xs[rr][kk] = x2[(size_t)(r0 + rr) * HID + kk];
    }
    __syncthreads();
    int j = threadIdx.x;
    if (j < NHEAD) {
        float a0 = 0.f, a1 = 0.f, a2 = 0.f, a3 = 0.f;
        if (j < NCLS) {
            for (int k = 0; k < HID; ++k) {
                float w = wc[k * NCLS + j];
                a0 = fmaf(xs[0][k], w, a0);
                a1 = fmaf(xs[1][k], w, a1);
                a2 = fmaf(xs[2][k], w, a2);
                a3 = fmaf(xs[3][k], w, a3);
            }
            float b = bc[j];
            a0 += b; a1 += b; a2 += b; a3 += b;
        } else {
            int jb = j - NCLS;
            for (int k = 0; k < HID; ++k) {
                float w = wb[k * 84 + jb];
                a0 = fmaf(xs[0][k], w, a0);
                a1 = fmaf(xs[1][k], w, a1);
                a2 = fmaf(xs[2][k], w, a2);
                a3 = fmaf(xs[3][k], w, a3);
            }
            float b = bb[jb];
            a0 += b; a1 += b; a2 += b; a3 += b;
        }
        logits[(size_t)(r0 + 0) * NHEAD + j] = a0;
        logits[(size_t)(r0 + 1) * NHEAD + j] = a1;
        logits[(size_t)(r0 + 2) * NHEAD + j] = a2;
        logits[(size_t)(r0 + 3) * NHEAD + j] = a3;
    }
}

// ---------------- softmax + decode + candidates + class-major offset boxes ----------------
__global__ __launch_bounds__(256) void k_prep(const float* __restrict__ logits,
                                              const float* __restrict__ rois,
                                              float* __restrict__ boxes,
                                              float* __restrict__ cand,
                                              float* __restrict__ boxesT) {
    int n = blockIdx.x * 256 + threadIdx.x;
    if (n >= NPROP) return;
    const float* L = logits + (size_t)n * NHEAD;
    float m = L[0];
    #pragma unroll
    for (int k = 1; k < NCLS; ++k) m = fmaxf(m, L[k]);
    float sum = 0.f;
    #pragma unroll
    for (int k = 0; k < NCLS; ++k) sum += expf(L[k] - m);

    float p0 = rois[n * 4 + 0], p1 = rois[n * 4 + 1];
    float p2 = rois[n * 4 + 2], p3 = rois[n * 4 + 3];
    float w = p2 - p0, h = p3 - p1;
    float cx = p0 + 0.5f * w, cy = p1 + 0.5f * h;

    for (int k = 1; k < NCLS; ++k) {
        int i = n * 20 + (k - 1);
        float s = expf(L[k] - m) / sum;
        const float* D = L + NCLS + k * 4;
        float dx = D[0], dy = D[1], dw = D[2], dh = D[3];
        float pcx = dx * w + cx;
        float pcy = dy * h + cy;
        float pw = expf(dw) * w;
        float ph = expf(dh) * h;
        float b0 = pcx - 0.5f * pw;
        float b1 = pcy - 0.5f * ph;
        float b2 = pcx + 0.5f * pw;
        float b3 = pcy + 0.5f * ph;
        boxes[(size_t)i * 4 + 0] = b0;
        boxes[(size_t)i * 4 + 1] = b1;
        boxes[(size_t)i * 4 + 2] = b2;
        boxes[(size_t)i * 4 + 3] = b3;
        cand[i] = (s > SCORE_T) ? s : -__builtin_inff();
        float offv = (float)k * 10000.0f;   // label = k, same f32 ops as reference
        ((float4*)boxesT)[(k - 1) * 1024 + n] =
            make_float4(b0 + offv, b1 + offv, b2 + offv, b3 + offv);
    }
}

// ---------------- per-class NMS: greedy in registers, 20 concurrent blocks ----------------
__global__ __launch_bounds__(256) void k_nms_cls(const float* __restrict__ cand,
                                                 const float* __restrict__ boxesT,
                                                 unsigned long long* __restrict__ accG,
                                                 int* __restrict__ accN) {
    __shared__ unsigned long long gkeys[2];      // ping-pong argmax
    __shared__ unsigned long long accL[MAXDET];  // picked keys
    __shared__ float sb4[4];                     // winner offset box broadcast
    __shared__ int sM;
    int tid = threadIdx.x;
    int c = blockIdx.x;   // class 0..19
    if (tid == 0) { gkeys[0] = 0ULL; gkeys[1] = 0ULL; sM = MAXDET; }

    float s[4];
    float4 bx[4];
    #pragma unroll
    for (int r = 0; r < 4; ++r) {
        int n = tid + (r << 8);
        if (n < NPROP) {
            s[r] = cand[n * 20 + c];
            bx[r] = ((const float4*)boxesT)[c * 1024 + n];
        } else {
            s[r] = -__builtin_inff();
            bx[r] = make_float4(0.f, 0.f, 0.f, 0.f);
        }
    }
    __syncthreads();

    for (int it = 0; it < MAXDET; ++it) {
        int cur = it & 1;
        unsigned long long k = 0ULL;
        #pragma unroll
        for (int r = 0; r < 4; ++r) {
            if (s[r] > 0.0f) {
                int n = tid + (r << 8);
                unsigned long long kk =
                    ((unsigned long long)__float_as_uint(s[r]) << 32) |
                    (unsigned long long)(0xFFFFFFFFu - (unsigned)(n * 20 + c));
                if (kk > k) k = kk;
            }
        }
        #pragma unroll
        for (int off = 32; off > 0; off >>= 1) {
            unsigned long long o = __shfl_down(k, off);
            if (o > k) k = o;
        }
        if ((tid & 63) == 0) atomicMax(&gkeys[cur], k);
        __syncthreads();   // A: argmax done
        unsigned long long g = gkeys[cur];
        if (tid == 0) {
            gkeys[cur ^ 1] = 0ULL;
            accL[it] = g;
            if (g == 0ULL) sM = it;
        }
        if (g != 0ULL) {
            int n_win = (int)(0xFFFFFFFFu - (unsigned)(g & 0xFFFFFFFFu)) / 20;
            if ((n_win & 255) == tid) {
                float4 b = bx[n_win >> 8];
                sb4[0] = b.x; sb4[1] = b.y; sb4[2] = b.z; sb4[3] = b.w;
            }
        }
        __syncthreads();   // B: sb4 + resets + sM visible
        if (g == 0ULL) break;  // uniform across block

        float q0 = sb4[0], q1 = sb4[1], q2 = sb4[2], q3 = sb4[3];
        float qa = (q2 - q0) * (q3 - q1);
        #pragma unroll
        for (int r = 0; r < 4; ++r) {
            if (s[r] > 0.0f) {
                float4 cb = bx[r];
                float ix1 = fmaxf(q0, cb.x), iy1 = fmaxf(q1, cb.y);
                float ix2 = fminf(q2, cb.z), iy2 = fminf(q3, cb.w);
                float inter = fmaxf(ix2 - ix1, 0.f) * fmaxf(iy2 - iy1, 0.f);
                float A2 = (cb.z - cb.x) * (cb.w - cb.y);
                float iou = inter / (qa + A2 - inter + 1e-9f);
                if (iou > NMS_T) s[r] = -__builtin_inff();
            }
        }
    }

    __syncthreads();
    int mm = sM;
    if (tid < mm) accG[c * MAXDET + tid] = accL[tid];
    if (tid == 0) accN[c] = mm;
}

// ---------------- merge: 20-way sorted merge by key, top-100, write outputs ----------------
__global__ __launch_bounds__(128) void k_nms_merge(const unsigned long long* __restrict__ accG,
                                                   const int* __restrict__ accN,
                                                   const float* __restrict__ boxes,
                                                   float* __restrict__ out) {
    __shared__ unsigned long long picks[MAXDET];
    int tid = threadIdx.x;
    if (tid < 64) {
        int c = tid;
        int cnt = (c < 20) ? accN[c] : 0;
        int ptr = 0;
        unsigned long long key = (cnt > 0) ? accG[c * MAXDET] : 0ULL;
        for (int it = 0; it < MAXDET; ++it) {
            unsigned long long k = key;
            #pragma unroll
            for (int off = 32; off > 0; off >>= 1) {
                unsigned long long o = __shfl_down(k, off);
                if (o > k) k = o;
            }
            unsigned long long g = __shfl(k, 0);
            if (tid == 0) picks[it] = g;
            if (g != 0ULL && key == g) {       // unique (idx embedded in key)
                ++ptr;
                key = (ptr < cnt) ? accG[c * MAXDET + ptr] : 0ULL;
            }
        }
    }
    __syncthreads();
    if (tid < MAXDET) {
        unsigned long long g = picks[tid];
        if (g != 0ULL) {
            int bi = (int)(0xFFFFFFFFu - (unsigned)(g & 0xFFFFFFFFu));
            float4 b = ((const float4*)boxes)[bi];
            out[tid * 4 + 0] = b.x; out[tid * 4 + 1] = b.y;
            out[tid * 4 + 2] = b.z; out[tid * 4 + 3] = b.w;
            out[400 + tid] = __uint_as_float((unsigned)(g >> 32));
            out[500 + tid] = (float)(bi - (bi / 20) * 20 + 1);
        } else {
            out[tid * 4 + 0] = 0.f; out[tid * 4 + 1] = 0.f;
            out[tid * 4 + 2] = 0.f; out[tid * 4 + 3] = 0.f;
            out[400 + tid] = 0.f;
            out[500 + tid] = 0.f;
        }
    }
}

extern "C" void kernel_launch(void* const* d_in, const int* in_sizes, int n_in,
                              void* d_out, int out_size, void* d_ws, size_t ws_size,
                              hipStream_t stream) {
    const float* fm   = (const float*)d_in[0];
    const float* rois = (const float*)d_in[1];
    const float* w1   = (const float*)d_in[2];
    const float* b1   = (const float*)d_in[3];
    const float* w2   = (const float*)d_in[4];
    const float* b2   = (const float*)d_in[5];
    const float* wc   = (const float*)d_in[6];
    const float* bc   = (const float*)d_in[7];
    const float* wb   = (const float*)d_in[8];
    const float* bb   = (const float*)d_in[9];
    float* out = (float*)d_out;

    float* ws = (float*)d_ws;
    float* fmT    = ws;                       // 2,560,000 f32 (reused as P after roi)
    float* P      = ws;                       // 2 x 1,048,576 f32 partials (split-K)
    float* poolr  = ws + 2560000;             // 12,544,000 f32-slots:
    f16*   poolh  = (f16*)poolr;              //   1000x12544 f16 (25.1MB)
    f16*   pooll  = (f16*)(poolr + 6272000);  //   1000x12544 f16 (25.1MB)
    float* x1r    = poolr + 12544000;         // 1,024,000 f32-slots:
    f16*   x1h    = (f16*)x1r;                //   1000x1024 f16
    f16*   x1l    = (f16*)(x1r + 512000);     //   1000x1024 f16
    float* x2     = x1r + 1024000;            // 1,024,000
    float* logits = x2 + 1024000;             // 105,000
    float* boxes  = logits + 105000;          // 80,000
    float* cand   = boxes + 80000;            // 20,000
    // reuse of pool region (GEMM1 consumed it before k_prep):
    float* boxesT = poolr;                                   // 81,920 floats
    unsigned long long* accG   = (unsigned long long*)(poolr + 131072);  // 2,000 u64
    int* accN                  = (int*)(poolr + 135072);                 // 20 ints

    k_transpose<<<157, 256, 0, stream>>>(fm, fmT);
    k_roi<<<NPROP, 256, 0, stream>>>(fmT, rois, poolh, pooll);
    k_gemm_mfma<<<dim3(16, 16, 2), 256, 0, stream>>>(poolh, pooll, w1, P, NPROP, FEAT, 196);
    k_fuse_f16<<<1000, 256, 0, stream>>>(P, b1, x1h, x1l);
    k_gemm_mfma<<<dim3(16, 16, 2), 256, 0, stream>>>(x1h, x1l, w2, P, NPROP, HID, 16);
    k_fuse_f32<<<1000, 256, 0, stream>>>(P, b2, x2);
    k_heads<<<250, 128, 0, stream>>>(x2, wc, bc, wb, bb, logits);
    k_prep<<<4, 256, 0, stream>>>(logits, rois, boxes, cand, boxesT);
    k_nms_cls<<<20, 256, 0, stream>>>(cand, boxesT, accG, accN);
    k_nms_merge<<<1, 128, 0, stream>>>(accG, accN, boxes, out);
}